// Round 5
// baseline (1882.388 us; speedup 1.0000x reference)
//
#include <hip/hip_runtime.h>
#include <hip/hip_bf16.h>
#include <math.h>

#define N_NODES 100000
#define N_EDGES 1600000
#define N_GRAPHS 1024
#define NB_SCAN ((N_NODES + 255) / 256)   // 391

// ---------------- layer 1: node linear (128 -> 64) x4 matrices ----------------
__global__ __launch_bounds__(256) void node_lin1(const float* __restrict__ x,
                          const float* __restrict__ Wq, const float* __restrict__ bq,
                          const float* __restrict__ Wk, const float* __restrict__ bk,
                          const float* __restrict__ Wv, const float* __restrict__ bv,
                          const float* __restrict__ Ws, const float* __restrict__ bs,
                          float* __restrict__ q, float* __restrict__ k,
                          float* __restrict__ v, float* __restrict__ s) {
    __shared__ float xs[16][128];
    int tid = threadIdx.x;
    int nb = blockIdx.x * 16;
    for (int i = tid; i < 16 * 128; i += 256) xs[i >> 7][i & 127] = x[(size_t)nb * 128 + i];
    __syncthreads();
    int w = tid >> 6, t = tid & 63;
    const float* W = (w == 0) ? Wq : (w == 1) ? Wk : (w == 2) ? Wv : Ws;
    const float* b = (w == 0) ? bq : (w == 1) ? bk : (w == 2) ? bv : bs;
    float* out = (w == 0) ? q : (w == 1) ? k : (w == 2) ? v : s;
    float acc[16];
#pragma unroll
    for (int n = 0; n < 16; ++n) acc[n] = 0.f;
#pragma unroll 4
    for (int j = 0; j < 128; ++j) {
        float wv = W[j * 64 + t];
#pragma unroll
        for (int n = 0; n < 16; ++n) acc[n] += xs[n][j] * wv;
    }
    float bb = b[t];
#pragma unroll
    for (int n = 0; n < 16; ++n) {
        int nn = nb + n;
        if (nn < N_NODES) out[(size_t)nn * 64 + t] = acc[n] + bb;
    }
}

// ---------------- layer 2: node linear (64 -> 16) x4 ----------------
__global__ __launch_bounds__(256) void node_lin2(const float* __restrict__ h,
                          const float* __restrict__ Wq, const float* __restrict__ bq,
                          const float* __restrict__ Wk, const float* __restrict__ bk,
                          const float* __restrict__ Wv, const float* __restrict__ bv,
                          const float* __restrict__ Ws, const float* __restrict__ bs,
                          float* __restrict__ q, float* __restrict__ k,
                          float* __restrict__ v, float* __restrict__ s) {
    __shared__ float hs[32][65];
    int tid = threadIdx.x;
    int nb = blockIdx.x * 32;
    for (int i = tid; i < 32 * 64; i += 256) {
        int nn = nb + (i >> 6);
        hs[i >> 6][i & 63] = (nn < N_NODES) ? h[(size_t)nb * 64 + i] : 0.f;
    }
    __syncthreads();
    int w = tid >> 6, t = tid & 63, g = t >> 4, c = t & 15;
    const float* W = (w == 0) ? Wq : (w == 1) ? Wk : (w == 2) ? Wv : Ws;
    const float* b = (w == 0) ? bq : (w == 1) ? bk : (w == 2) ? bv : bs;
    float* out = (w == 0) ? q : (w == 1) ? k : (w == 2) ? v : s;
    float acc[8];
#pragma unroll
    for (int n = 0; n < 8; ++n) acc[n] = 0.f;
#pragma unroll 4
    for (int j = 0; j < 64; ++j) {
        float wv = W[j * 16 + c];
#pragma unroll
        for (int n = 0; n < 8; ++n) acc[n] += hs[g * 8 + n][j] * wv;
    }
    float bb = b[c];
#pragma unroll
    for (int n = 0; n < 8; ++n) {
        int nn = nb + g * 8 + n;
        if (nn < N_NODES) out[(size_t)nn * 16 + c] = acc[n] + bb;
    }
}

// ---------------- CSR build: histogram -> scan -> scatter ----------------
__global__ void hist_kernel(const int* __restrict__ ei, int* __restrict__ deg) {
    int e = blockIdx.x * blockDim.x + threadIdx.x;
    if (e < N_EDGES) atomicAdd(deg + ei[N_EDGES + e], 1);
}

__global__ __launch_bounds__(256) void scan_block(const int* __restrict__ deg,
        int* __restrict__ rowptr, int* __restrict__ bsum) {
    __shared__ int sd[256];
    int i = blockIdx.x * 256 + threadIdx.x;
    int v = (i < N_NODES) ? deg[i] : 0;
    sd[threadIdx.x] = v;
    __syncthreads();
    for (int off = 1; off < 256; off <<= 1) {
        int add = (threadIdx.x >= off) ? sd[threadIdx.x - off] : 0;
        __syncthreads();
        sd[threadIdx.x] += add;
        __syncthreads();
    }
    if (i < N_NODES) rowptr[i] = sd[threadIdx.x] - v;   // exclusive within block
    if (threadIdx.x == 255) bsum[blockIdx.x] = sd[255];
}

__global__ __launch_bounds__(512) void scan_bsum(int* __restrict__ bsum) {
    __shared__ int sd[512];
    int t = threadIdx.x;
    int v = (t < NB_SCAN) ? bsum[t] : 0;
    sd[t] = v;
    __syncthreads();
    for (int off = 1; off < 512; off <<= 1) {
        int add = (t >= off) ? sd[t - off] : 0;
        __syncthreads();
        sd[t] += add;
        __syncthreads();
    }
    if (t < NB_SCAN) bsum[t] = sd[t] - v;               // exclusive
}

__global__ void scan_add(int* __restrict__ rowptr, int* __restrict__ cursor,
                         const int* __restrict__ bsum) {
    int i = blockIdx.x * blockDim.x + threadIdx.x;
    if (i < N_NODES) {
        int r = rowptr[i] + bsum[i >> 8];
        rowptr[i] = r;
        cursor[i] = r;
    }
    if (i == 0) rowptr[N_NODES] = N_EDGES;
}

__global__ void scatter_kernel(const int* __restrict__ ei, int* __restrict__ cursor,
                               int2* __restrict__ sorted) {
    int e = blockIdx.x * blockDim.x + threadIdx.x;
    if (e >= N_EDGES) return;
    int d = ei[N_EDGES + e];
    int pos = atomicAdd(cursor + d, 1);
    sorted[pos] = make_int2(ei[e], e);   // (src, eid)
}

// ---------------- layer 1: per-dst fused attention, 4-edge pipelined ----------------
// one wave per dst node; 64 lanes = 64 channels
__global__ __launch_bounds__(256) void agg_l1(const int2* __restrict__ sorted,
        const int* __restrict__ rowptr, const float* __restrict__ ea,
        const float* __restrict__ q, const float* __restrict__ k,
        const float* __restrict__ v, const float* __restrict__ We,
        float* __restrict__ h /* in: skip, out: relu result */) {
    int w = threadIdx.x >> 6, t = threadIdx.x & 63;
    int n = blockIdx.x * 4 + w;
    if (n >= N_NODES) return;
    float we[32];
#pragma unroll
    for (int j = 0; j < 32; ++j) we[j] = We[j * 64 + t];
    float qv = q[(size_t)n * 64 + t];
    int beg = rowptr[n], end = rowptr[n + 1];
    float den = 0.f, acc = 0.f;
    int idx = beg;
    // ---- 4-edge pipelined main loop ----
    for (; idx + 4 <= end; idx += 4) {
        int2 se0 = sorted[idx], se1 = sorted[idx + 1];
        int2 se2 = sorted[idx + 2], se3 = sorted[idx + 3];
        float kv0 = k[(size_t)se0.x * 64 + t], kv1 = k[(size_t)se1.x * 64 + t];
        float kv2 = k[(size_t)se2.x * 64 + t], kv3 = k[(size_t)se3.x * 64 + t];
        float vv0 = v[(size_t)se0.x * 64 + t], vv1 = v[(size_t)se1.x * 64 + t];
        float vv2 = v[(size_t)se2.x * 64 + t], vv3 = v[(size_t)se3.x * 64 + t];
        const float4* ep0 = (const float4*)(ea + (size_t)se0.y * 32);
        const float4* ep1 = (const float4*)(ea + (size_t)se1.y * 32);
        const float4* ep2 = (const float4*)(ea + (size_t)se2.y * 32);
        const float4* ep3 = (const float4*)(ea + (size_t)se3.y * 32);
        float et0 = 0.f, et1 = 0.f, et2 = 0.f, et3 = 0.f;
#pragma unroll
        for (int r = 0; r < 8; ++r) {
            float4 f0 = ep0[r], f1 = ep1[r], f2 = ep2[r], f3 = ep3[r];
            float w0 = we[4 * r], w1 = we[4 * r + 1], w2 = we[4 * r + 2], w3 = we[4 * r + 3];
            et0 += f0.x * w0 + f0.y * w1 + f0.z * w2 + f0.w * w3;
            et1 += f1.x * w0 + f1.y * w1 + f1.z * w2 + f1.w * w3;
            et2 += f2.x * w0 + f2.y * w1 + f2.z * w2 + f2.w * w3;
            et3 += f3.x * w0 + f3.y * w1 + f3.z * w2 + f3.w * w3;
        }
        float p0 = qv * (kv0 + et0), p1 = qv * (kv1 + et1);
        float p2 = qv * (kv2 + et2), p3 = qv * (kv3 + et3);
#pragma unroll
        for (int m = 32; m > 0; m >>= 1) {
            p0 += __shfl_xor(p0, m, 64);
            p1 += __shfl_xor(p1, m, 64);
            p2 += __shfl_xor(p2, m, 64);
            p3 += __shfl_xor(p3, m, 64);
        }
        float a0 = __expf(p0 * 0.125f), a1 = __expf(p1 * 0.125f);
        float a2 = __expf(p2 * 0.125f), a3 = __expf(p3 * 0.125f);
        den += (a0 + a1) + (a2 + a3);
        acc += a0 * (vv0 + et0) + a1 * (vv1 + et1) + a2 * (vv2 + et2) + a3 * (vv3 + et3);
    }
    // ---- tail ----
    for (; idx < end; ++idx) {
        int2 se = sorted[idx];
        const float4* eap = (const float4*)(ea + (size_t)se.y * 32);
        float kv = k[(size_t)se.x * 64 + t];
        float vv = v[(size_t)se.x * 64 + t];
        float et = 0.f;
#pragma unroll
        for (int r = 0; r < 8; ++r) {
            float4 f = eap[r];
            et += f.x * we[4 * r] + f.y * we[4 * r + 1] +
                  f.z * we[4 * r + 2] + f.w * we[4 * r + 3];
        }
        float p = qv * (kv + et);
#pragma unroll
        for (int m = 32; m > 0; m >>= 1) p += __shfl_xor(p, m, 64);
        float a = __expf(p * 0.125f);
        den += a;
        acc += a * (vv + et);
    }
    size_t o = (size_t)n * 64 + t;
    float r2 = acc / (den + 1e-16f) + h[o];
    h[o] = r2 > 0.f ? r2 : 0.f;
}

// ---------------- layer 2: per-dst fused attention + mean-pool ----------------
// one wave per dst; 4 groups x 16 lanes: group g processes edges idx = beg+g, +4...
__global__ __launch_bounds__(256) void agg_l2(const int2* __restrict__ sorted,
        const int* __restrict__ rowptr, const float* __restrict__ ea,
        const float* __restrict__ q, const float* __restrict__ k,
        const float* __restrict__ v, const float* __restrict__ We,
        const float* __restrict__ skip, const int* __restrict__ batch,
        float* __restrict__ sums, float* __restrict__ cnt) {
    int w = threadIdx.x >> 6, t = threadIdx.x & 63;
    int n = blockIdx.x * 4 + w;
    if (n >= N_NODES) return;
    int g = t >> 4, c = t & 15;
    float we[32];
#pragma unroll
    for (int j = 0; j < 32; ++j) we[j] = We[j * 16 + c];
    float qv = q[(size_t)n * 16 + c];
    int beg = rowptr[n], end = rowptr[n + 1];
    float den = 0.f, acc = 0.f;
    for (int idx = beg + g; idx < end; idx += 4) {
        int2 se = sorted[idx];
        const float4* eap = (const float4*)(ea + (size_t)se.y * 32);
        float4 ef[8];
#pragma unroll
        for (int r = 0; r < 8; ++r) ef[r] = eap[r];
        float kv = k[(size_t)se.x * 16 + c];
        float vv = v[(size_t)se.x * 16 + c];
        float et = 0.f;
#pragma unroll
        for (int r = 0; r < 8; ++r)
            et += ef[r].x * we[4 * r] + ef[r].y * we[4 * r + 1] +
                  ef[r].z * we[4 * r + 2] + ef[r].w * we[4 * r + 3];
        float p = qv * (kv + et);
        p += __shfl_xor(p, 8, 64);
        p += __shfl_xor(p, 4, 64);
        p += __shfl_xor(p, 2, 64);
        p += __shfl_xor(p, 1, 64);
        float a = __expf(p * 0.25f);
        den += a;
        acc += a * (vv + et);
    }
    den += __shfl_xor(den, 16, 64);
    den += __shfl_xor(den, 32, 64);
    acc += __shfl_xor(acc, 16, 64);
    acc += __shfl_xor(acc, 32, 64);
    if (t < 16) {
        float r2 = acc / (den + 1e-16f) + skip[(size_t)n * 16 + c];
        r2 = r2 > 0.f ? r2 : 0.f;
        int gb = batch[n];
        atomicAdd(sums + gb * 16 + c, r2);
        if (c == 0) atomicAdd(cnt + gb, 1.0f);
    }
}

// ---------------- final fc + sigmoid ----------------
__global__ void final_fc(const float* __restrict__ sums, const float* __restrict__ cnt,
                         const float* __restrict__ Wf, const float* __restrict__ bf,
                         float* __restrict__ out) {
    int g = blockIdx.x * blockDim.x + threadIdx.x;
    if (g >= N_GRAPHS) return;
    float cc = cnt[g];
    cc = cc > 1.f ? cc : 1.f;
    float acc = bf[0];
#pragma unroll
    for (int c = 0; c < 16; ++c) acc += (sums[g * 16 + c] / cc) * Wf[c];
    out[g] = 1.f / (1.f + expf(-acc));
}

extern "C" void kernel_launch(void* const* d_in, const int* in_sizes, int n_in,
                              void* d_out, int out_size, void* d_ws, size_t ws_size,
                              hipStream_t stream) {
    const float* x    = (const float*)d_in[0];
    const float* ea   = (const float*)d_in[1];
    const float* Wq1  = (const float*)d_in[2];
    const float* bq1  = (const float*)d_in[3];
    const float* Wk1  = (const float*)d_in[4];
    const float* bk1  = (const float*)d_in[5];
    const float* Wv1  = (const float*)d_in[6];
    const float* bv1  = (const float*)d_in[7];
    const float* We1  = (const float*)d_in[8];
    const float* Ws1  = (const float*)d_in[9];
    const float* bs1  = (const float*)d_in[10];
    const float* Wq2  = (const float*)d_in[11];
    const float* bq2  = (const float*)d_in[12];
    const float* Wk2  = (const float*)d_in[13];
    const float* bk2  = (const float*)d_in[14];
    const float* Wv2  = (const float*)d_in[15];
    const float* bv2  = (const float*)d_in[16];
    const float* We2  = (const float*)d_in[17];
    const float* Ws2  = (const float*)d_in[18];
    const float* bs2  = (const float*)d_in[19];
    const float* Wf   = (const float*)d_in[20];
    const float* bf   = (const float*)d_in[21];
    const int*   ei   = (const int*)d_in[22];
    const int*   batch= (const int*)d_in[23];
    float* out = (float*)d_out;

    // -------- workspace layout --------
    float* ws = (float*)d_ws;
    size_t off = 0;
    float* q1 = ws + off; off += (size_t)N_NODES * 64;
    float* k1 = ws + off; off += (size_t)N_NODES * 64;
    float* v1 = ws + off; off += (size_t)N_NODES * 64;
    float* s1 = ws + off; off += (size_t)N_NODES * 64;   // skip -> h1
    float* q2 = ws + off; off += (size_t)N_NODES * 16;
    float* k2 = ws + off; off += (size_t)N_NODES * 16;
    float* v2 = ws + off; off += (size_t)N_NODES * 16;
    float* s2 = ws + off; off += (size_t)N_NODES * 16;   // skip for layer 2
    int2* sorted = (int2*)(ws + off); off += (size_t)N_EDGES * 2;
    int* rowptr  = (int*)(ws + off);  off += N_NODES + 2;
    int* cursor  = (int*)(ws + off);  off += N_NODES;
    int* bsum    = (int*)(ws + off);  off += 512;
    // ---- contiguous zero block ----
    float* zerop = ws + off;
    int*   deg   = (int*)(ws + off);  off += N_NODES;
    float* sums  = ws + off;          off += (size_t)N_GRAPHS * 16;
    float* cnt   = ws + off;          off += N_GRAPHS;
    size_t zero_bytes = ((size_t)N_NODES + N_GRAPHS * 16 + N_GRAPHS) * sizeof(float);
    hipMemsetAsync(zerop, 0, zero_bytes, stream);

    // -------- CSR build (shared by both layers) --------
    hist_kernel<<<(N_EDGES + 255) / 256, 256, 0, stream>>>(ei, deg);
    scan_block<<<NB_SCAN, 256, 0, stream>>>(deg, rowptr, bsum);
    scan_bsum<<<1, 512, 0, stream>>>(bsum);
    scan_add<<<NB_SCAN, 256, 0, stream>>>(rowptr, cursor, bsum);
    scatter_kernel<<<(N_EDGES + 255) / 256, 256, 0, stream>>>(ei, cursor, sorted);

    // -------- layer 1 --------
    node_lin1<<<(N_NODES + 15) / 16, 256, 0, stream>>>(x, Wq1, bq1, Wk1, bk1, Wv1, bv1,
                                                       Ws1, bs1, q1, k1, v1, s1);
    agg_l1<<<(N_NODES + 3) / 4, 256, 0, stream>>>(sorted, rowptr, ea, q1, k1, v1, We1, s1);

    // -------- layer 2 --------
    node_lin2<<<(N_NODES + 31) / 32, 256, 0, stream>>>(s1, Wq2, bq2, Wk2, bk2, Wv2, bv2,
                                                       Ws2, bs2, q2, k2, v2, s2);
    agg_l2<<<(N_NODES + 3) / 4, 256, 0, stream>>>(sorted, rowptr, ea, q2, k2, v2, We2,
                                                  s2, batch, sums, cnt);

    // -------- final fc --------
    final_fc<<<(N_GRAPHS + 255) / 256, 256, 0, stream>>>(sums, cnt, Wf, bf, out);
}

// Round 6
// 1272.970 us; speedup vs baseline: 1.4787x; 1.4787x over previous
//
#include <hip/hip_runtime.h>
#include <hip/hip_bf16.h>
#include <math.h>

#define N_NODES 100000
#define N_EDGES 1600000
#define N_GRAPHS 1024
#define NB_SCAN ((N_NODES + 255) / 256)   // 391

// ---------------- layer 1: node linear (128 -> 64) x4 matrices ----------------
// outputs: q [N,64], kv packed [N,128] (k at +0, v at +64), s [N,64]
__global__ __launch_bounds__(256) void node_lin1(const float* __restrict__ x,
                          const float* __restrict__ Wq, const float* __restrict__ bq,
                          const float* __restrict__ Wk, const float* __restrict__ bk,
                          const float* __restrict__ Wv, const float* __restrict__ bv,
                          const float* __restrict__ Ws, const float* __restrict__ bs,
                          float* __restrict__ q, float* __restrict__ kv,
                          float* __restrict__ s) {
    __shared__ float xs[16][128];
    int tid = threadIdx.x;
    int nb = blockIdx.x * 16;
    for (int i = tid; i < 16 * 128; i += 256) xs[i >> 7][i & 127] = x[(size_t)nb * 128 + i];
    __syncthreads();
    int w = tid >> 6, t = tid & 63;
    const float* W = (w == 0) ? Wq : (w == 1) ? Wk : (w == 2) ? Wv : Ws;
    const float* b = (w == 0) ? bq : (w == 1) ? bk : (w == 2) ? bv : bs;
    float acc[16];
#pragma unroll
    for (int n = 0; n < 16; ++n) acc[n] = 0.f;
#pragma unroll 4
    for (int j = 0; j < 128; ++j) {
        float wv = W[j * 64 + t];
#pragma unroll
        for (int n = 0; n < 16; ++n) acc[n] += xs[n][j] * wv;
    }
    float bb = b[t];
#pragma unroll
    for (int n = 0; n < 16; ++n) {
        int nn = nb + n;
        if (nn >= N_NODES) break;
        float r = acc[n] + bb;
        if (w == 0)      q[(size_t)nn * 64 + t] = r;
        else if (w == 1) kv[(size_t)nn * 128 + t] = r;
        else if (w == 2) kv[(size_t)nn * 128 + 64 + t] = r;
        else             s[(size_t)nn * 64 + t] = r;
    }
}

// ---------------- layer 2: node linear (64 -> 16) x4 ----------------
// outputs: q [N,16], kv packed [N,32] (k at +0, v at +16), s [N,16]
__global__ __launch_bounds__(256) void node_lin2(const float* __restrict__ h,
                          const float* __restrict__ Wq, const float* __restrict__ bq,
                          const float* __restrict__ Wk, const float* __restrict__ bk,
                          const float* __restrict__ Wv, const float* __restrict__ bv,
                          const float* __restrict__ Ws, const float* __restrict__ bs,
                          float* __restrict__ q, float* __restrict__ kv,
                          float* __restrict__ s) {
    __shared__ float hs[32][65];
    int tid = threadIdx.x;
    int nb = blockIdx.x * 32;
    for (int i = tid; i < 32 * 64; i += 256) {
        int nn = nb + (i >> 6);
        hs[i >> 6][i & 63] = (nn < N_NODES) ? h[(size_t)nb * 64 + i] : 0.f;
    }
    __syncthreads();
    int w = tid >> 6, t = tid & 63, g = t >> 4, c = t & 15;
    const float* W = (w == 0) ? Wq : (w == 1) ? Wk : (w == 2) ? Wv : Ws;
    const float* b = (w == 0) ? bq : (w == 1) ? bk : (w == 2) ? bv : bs;
    float acc[8];
#pragma unroll
    for (int n = 0; n < 8; ++n) acc[n] = 0.f;
#pragma unroll 4
    for (int j = 0; j < 64; ++j) {
        float wv = W[j * 16 + c];
#pragma unroll
        for (int n = 0; n < 8; ++n) acc[n] += hs[g * 8 + n][j] * wv;
    }
    float bb = b[c];
#pragma unroll
    for (int n = 0; n < 8; ++n) {
        int nn = nb + g * 8 + n;
        if (nn >= N_NODES) break;
        float r = acc[n] + bb;
        if (w == 0)      q[(size_t)nn * 16 + c] = r;
        else if (w == 1) kv[(size_t)nn * 32 + c] = r;
        else if (w == 2) kv[(size_t)nn * 32 + 16 + c] = r;
        else             s[(size_t)nn * 16 + c] = r;
    }
}

// ---------------- CSR build: histogram -> scan -> scatter ----------------
__global__ void hist_kernel(const int* __restrict__ ei, int* __restrict__ deg) {
    int e = blockIdx.x * blockDim.x + threadIdx.x;
    if (e < N_EDGES) atomicAdd(deg + ei[N_EDGES + e], 1);
}

__global__ __launch_bounds__(256) void scan_block(const int* __restrict__ deg,
        int* __restrict__ rowptr, int* __restrict__ bsum) {
    __shared__ int sd[256];
    int i = blockIdx.x * 256 + threadIdx.x;
    int v = (i < N_NODES) ? deg[i] : 0;
    sd[threadIdx.x] = v;
    __syncthreads();
    for (int off = 1; off < 256; off <<= 1) {
        int add = (threadIdx.x >= off) ? sd[threadIdx.x - off] : 0;
        __syncthreads();
        sd[threadIdx.x] += add;
        __syncthreads();
    }
    if (i < N_NODES) rowptr[i] = sd[threadIdx.x] - v;   // exclusive within block
    if (threadIdx.x == 255) bsum[blockIdx.x] = sd[255];
}

__global__ __launch_bounds__(512) void scan_bsum(int* __restrict__ bsum) {
    __shared__ int sd[512];
    int t = threadIdx.x;
    int v = (t < NB_SCAN) ? bsum[t] : 0;
    sd[t] = v;
    __syncthreads();
    for (int off = 1; off < 512; off <<= 1) {
        int add = (t >= off) ? sd[t - off] : 0;
        __syncthreads();
        sd[t] += add;
        __syncthreads();
    }
    if (t < NB_SCAN) bsum[t] = sd[t] - v;               // exclusive
}

__global__ void scan_add(int* __restrict__ rowptr, int* __restrict__ cursor,
                         const int* __restrict__ bsum) {
    int i = blockIdx.x * blockDim.x + threadIdx.x;
    if (i < N_NODES) {
        int r = rowptr[i] + bsum[i >> 8];
        rowptr[i] = r;
        cursor[i] = r;
    }
    if (i == 0) rowptr[N_NODES] = N_EDGES;
}

__global__ void scatter_kernel(const int* __restrict__ ei, int* __restrict__ cursor,
                               int2* __restrict__ sorted) {
    int e = blockIdx.x * blockDim.x + threadIdx.x;
    if (e >= N_EDGES) return;
    int d = ei[N_EDGES + e];
    int pos = atomicAdd(cursor + d, 1);
    sorted[pos] = make_int2(ei[e], e);   // (src, eid)
}

// ---------------- layer 1: per-dst fused attention, 2-edge ILP ----------------
// one wave per dst node; 64 lanes = 64 channels; kv packed [N,128]
__global__ __launch_bounds__(256) void agg_l1(const int2* __restrict__ sorted,
        const int* __restrict__ rowptr, const float* __restrict__ ea,
        const float* __restrict__ q, const float* __restrict__ kv,
        const float* __restrict__ We,
        float* __restrict__ h /* in: skip, out: relu result */) {
    int w = threadIdx.x >> 6, t = threadIdx.x & 63;
    int n = blockIdx.x * 4 + w;
    if (n >= N_NODES) return;
    float we[32];
#pragma unroll
    for (int j = 0; j < 32; ++j) we[j] = We[j * 64 + t];
    float qv = q[(size_t)n * 64 + t];
    int beg = rowptr[n], end = rowptr[n + 1];
    float den = 0.f, acc = 0.f;
    int idx = beg;
    // ---- 2-edge ILP main loop ----
    for (; idx + 2 <= end; idx += 2) {
        int2 se0 = sorted[idx], se1 = sorted[idx + 1];
        const float* kp0 = kv + (size_t)se0.x * 128;
        const float* kp1 = kv + (size_t)se1.x * 128;
        float kv0 = kp0[t], vv0 = kp0[64 + t];
        float kv1 = kp1[t], vv1 = kp1[64 + t];
        const float4* e0 = (const float4*)(ea + (size_t)se0.y * 32);
        const float4* e1 = (const float4*)(ea + (size_t)se1.y * 32);
        float et0 = 0.f, et1 = 0.f;
#pragma unroll
        for (int r = 0; r < 8; ++r) {
            float4 f0 = e0[r], f1 = e1[r];
            float w0 = we[4 * r], w1 = we[4 * r + 1], w2 = we[4 * r + 2], w3 = we[4 * r + 3];
            et0 += f0.x * w0 + f0.y * w1 + f0.z * w2 + f0.w * w3;
            et1 += f1.x * w0 + f1.y * w1 + f1.z * w2 + f1.w * w3;
        }
        float p0 = qv * (kv0 + et0), p1 = qv * (kv1 + et1);
#pragma unroll
        for (int m = 32; m > 0; m >>= 1) {
            p0 += __shfl_xor(p0, m, 64);
            p1 += __shfl_xor(p1, m, 64);
        }
        float a0 = __expf(p0 * 0.125f), a1 = __expf(p1 * 0.125f);
        den += a0 + a1;
        acc += a0 * (vv0 + et0) + a1 * (vv1 + et1);
    }
    // ---- tail (0 or 1 edge) ----
    if (idx < end) {
        int2 se = sorted[idx];
        const float* kp = kv + (size_t)se.x * 128;
        float kvx = kp[t], vvx = kp[64 + t];
        const float4* eap = (const float4*)(ea + (size_t)se.y * 32);
        float et = 0.f;
#pragma unroll
        for (int r = 0; r < 8; ++r) {
            float4 f = eap[r];
            et += f.x * we[4 * r] + f.y * we[4 * r + 1] +
                  f.z * we[4 * r + 2] + f.w * we[4 * r + 3];
        }
        float p = qv * (kvx + et);
#pragma unroll
        for (int m = 32; m > 0; m >>= 1) p += __shfl_xor(p, m, 64);
        float a = __expf(p * 0.125f);
        den += a;
        acc += a * (vvx + et);
    }
    size_t o = (size_t)n * 64 + t;
    float r2 = acc / (den + 1e-16f) + h[o];
    h[o] = r2 > 0.f ? r2 : 0.f;
}

// ---------------- layer 2: per-dst fused attention + mean-pool ----------------
// one wave per dst; 4 groups x 16 lanes; kv packed [N,32]
__global__ __launch_bounds__(256) void agg_l2(const int2* __restrict__ sorted,
        const int* __restrict__ rowptr, const float* __restrict__ ea,
        const float* __restrict__ q, const float* __restrict__ kv,
        const float* __restrict__ We,
        const float* __restrict__ skip, const int* __restrict__ batch,
        float* __restrict__ sums, float* __restrict__ cnt) {
    int w = threadIdx.x >> 6, t = threadIdx.x & 63;
    int n = blockIdx.x * 4 + w;
    if (n >= N_NODES) return;
    int g = t >> 4, c = t & 15;
    float we[32];
#pragma unroll
    for (int j = 0; j < 32; ++j) we[j] = We[j * 16 + c];
    float qv = q[(size_t)n * 16 + c];
    int beg = rowptr[n], end = rowptr[n + 1];
    float den = 0.f, acc = 0.f;
    for (int idx = beg + g; idx < end; idx += 4) {
        int2 se = sorted[idx];
        const float* kp = kv + (size_t)se.x * 32;
        float kvx = kp[c], vvx = kp[16 + c];
        const float4* eap = (const float4*)(ea + (size_t)se.y * 32);
        float et = 0.f;
#pragma unroll
        for (int r = 0; r < 8; ++r) {
            float4 f = eap[r];
            et += f.x * we[4 * r] + f.y * we[4 * r + 1] +
                  f.z * we[4 * r + 2] + f.w * we[4 * r + 3];
        }
        float p = qv * (kvx + et);
        p += __shfl_xor(p, 8, 64);
        p += __shfl_xor(p, 4, 64);
        p += __shfl_xor(p, 2, 64);
        p += __shfl_xor(p, 1, 64);
        float a = __expf(p * 0.25f);
        den += a;
        acc += a * (vvx + et);
    }
    den += __shfl_xor(den, 16, 64);
    den += __shfl_xor(den, 32, 64);
    acc += __shfl_xor(acc, 16, 64);
    acc += __shfl_xor(acc, 32, 64);
    if (t < 16) {
        float r2 = acc / (den + 1e-16f) + skip[(size_t)n * 16 + c];
        r2 = r2 > 0.f ? r2 : 0.f;
        int gb = batch[n];
        atomicAdd(sums + gb * 16 + c, r2);
        if (c == 0) atomicAdd(cnt + gb, 1.0f);
    }
}

// ---------------- final fc + sigmoid ----------------
__global__ void final_fc(const float* __restrict__ sums, const float* __restrict__ cnt,
                         const float* __restrict__ Wf, const float* __restrict__ bf,
                         float* __restrict__ out) {
    int g = blockIdx.x * blockDim.x + threadIdx.x;
    if (g >= N_GRAPHS) return;
    float cc = cnt[g];
    cc = cc > 1.f ? cc : 1.f;
    float acc = bf[0];
#pragma unroll
    for (int c = 0; c < 16; ++c) acc += (sums[g * 16 + c] / cc) * Wf[c];
    out[g] = 1.f / (1.f + expf(-acc));
}

extern "C" void kernel_launch(void* const* d_in, const int* in_sizes, int n_in,
                              void* d_out, int out_size, void* d_ws, size_t ws_size,
                              hipStream_t stream) {
    const float* x    = (const float*)d_in[0];
    const float* ea   = (const float*)d_in[1];
    const float* Wq1  = (const float*)d_in[2];
    const float* bq1  = (const float*)d_in[3];
    const float* Wk1  = (const float*)d_in[4];
    const float* bk1  = (const float*)d_in[5];
    const float* Wv1  = (const float*)d_in[6];
    const float* bv1  = (const float*)d_in[7];
    const float* We1  = (const float*)d_in[8];
    const float* Ws1  = (const float*)d_in[9];
    const float* bs1  = (const float*)d_in[10];
    const float* Wq2  = (const float*)d_in[11];
    const float* bq2  = (const float*)d_in[12];
    const float* Wk2  = (const float*)d_in[13];
    const float* bk2  = (const float*)d_in[14];
    const float* Wv2  = (const float*)d_in[15];
    const float* bv2  = (const float*)d_in[16];
    const float* We2  = (const float*)d_in[17];
    const float* Ws2  = (const float*)d_in[18];
    const float* bs2  = (const float*)d_in[19];
    const float* Wf   = (const float*)d_in[20];
    const float* bf   = (const float*)d_in[21];
    const int*   ei   = (const int*)d_in[22];
    const int*   batch= (const int*)d_in[23];
    float* out = (float*)d_out;

    // -------- workspace layout --------
    float* ws = (float*)d_ws;
    size_t off = 0;
    float* q1  = ws + off; off += (size_t)N_NODES * 64;
    float* kv1 = ws + off; off += (size_t)N_NODES * 128;  // k/v packed
    float* s1  = ws + off; off += (size_t)N_NODES * 64;   // skip -> h1
    float* q2  = ws + off; off += (size_t)N_NODES * 16;
    float* kv2 = ws + off; off += (size_t)N_NODES * 32;   // k/v packed
    float* s2  = ws + off; off += (size_t)N_NODES * 16;   // skip for layer 2
    int2* sorted = (int2*)(ws + off); off += (size_t)N_EDGES * 2;
    int* rowptr  = (int*)(ws + off);  off += N_NODES + 2;
    int* cursor  = (int*)(ws + off);  off += N_NODES;
    int* bsum    = (int*)(ws + off);  off += 512;
    // ---- contiguous zero block ----
    float* zerop = ws + off;
    int*   deg   = (int*)(ws + off);  off += N_NODES;
    float* sums  = ws + off;          off += (size_t)N_GRAPHS * 16;
    float* cnt   = ws + off;          off += N_GRAPHS;
    size_t zero_bytes = ((size_t)N_NODES + N_GRAPHS * 16 + N_GRAPHS) * sizeof(float);
    hipMemsetAsync(zerop, 0, zero_bytes, stream);

    // -------- CSR build (shared by both layers) --------
    hist_kernel<<<(N_EDGES + 255) / 256, 256, 0, stream>>>(ei, deg);
    scan_block<<<NB_SCAN, 256, 0, stream>>>(deg, rowptr, bsum);
    scan_bsum<<<1, 512, 0, stream>>>(bsum);
    scan_add<<<NB_SCAN, 256, 0, stream>>>(rowptr, cursor, bsum);
    scatter_kernel<<<(N_EDGES + 255) / 256, 256, 0, stream>>>(ei, cursor, sorted);

    // -------- layer 1 --------
    node_lin1<<<(N_NODES + 15) / 16, 256, 0, stream>>>(x, Wq1, bq1, Wk1, bk1, Wv1, bv1,
                                                       Ws1, bs1, q1, kv1, s1);
    agg_l1<<<(N_NODES + 3) / 4, 256, 0, stream>>>(sorted, rowptr, ea, q1, kv1, We1, s1);

    // -------- layer 2 --------
    node_lin2<<<(N_NODES + 31) / 32, 256, 0, stream>>>(s1, Wq2, bq2, Wk2, bk2, Wv2, bv2,
                                                       Ws2, bs2, q2, kv2, s2);
    agg_l2<<<(N_NODES + 3) / 4, 256, 0, stream>>>(sorted, rowptr, ea, q2, kv2, We2,
                                                  s2, batch, sums, cnt);

    // -------- final fc --------
    final_fc<<<(N_GRAPHS + 255) / 256, 256, 0, stream>>>(sums, cnt, Wf, bf, out);
}

// Round 7
// 997.014 us; speedup vs baseline: 1.8880x; 1.2768x over previous
//
#include <hip/hip_runtime.h>
#include <hip/hip_bf16.h>
#include <math.h>

#define N_NODES 100000
#define N_EDGES 1600000
#define N_GRAPHS 1024
#define NB_SCAN ((N_NODES + 255) / 256)   // 391

static __device__ __forceinline__ float bf2f(ushort u) {
    return __uint_as_float(((unsigned)u) << 16);
}
static __device__ __forceinline__ ushort f2bf(float f) {
    unsigned x = __float_as_uint(f);
    return (ushort)((x + 0x7fffu + ((x >> 16) & 1u)) >> 16);   // RNE
}

// ---------------- layer 1: node linear (128 -> 64) x4 matrices ----------------
// outputs: q [N,64] f32, kvt [N,64] uint (bf16 k lo | bf16 v hi), s [N,64] f32
__global__ __launch_bounds__(256) void node_lin1(const float* __restrict__ x,
                          const float* __restrict__ Wq, const float* __restrict__ bq,
                          const float* __restrict__ Wk, const float* __restrict__ bk,
                          const float* __restrict__ Wv, const float* __restrict__ bv,
                          const float* __restrict__ Ws, const float* __restrict__ bs,
                          float* __restrict__ q, uint* __restrict__ kvt,
                          float* __restrict__ s) {
    __shared__ float xs[16][128];
    int tid = threadIdx.x;
    int nb = blockIdx.x * 16;
    for (int i = tid; i < 16 * 128; i += 256) xs[i >> 7][i & 127] = x[(size_t)nb * 128 + i];
    __syncthreads();
    int w = tid >> 6, t = tid & 63;
    const float* W = (w == 0) ? Wq : (w == 1) ? Wk : (w == 2) ? Wv : Ws;
    const float* b = (w == 0) ? bq : (w == 1) ? bk : (w == 2) ? bv : bs;
    float acc[16];
#pragma unroll
    for (int n = 0; n < 16; ++n) acc[n] = 0.f;
#pragma unroll 4
    for (int j = 0; j < 128; ++j) {
        float wv = W[j * 64 + t];
#pragma unroll
        for (int n = 0; n < 16; ++n) acc[n] += xs[n][j] * wv;
    }
    float bb = b[t];
#pragma unroll
    for (int n = 0; n < 16; ++n) {
        int nn = nb + n;
        if (nn >= N_NODES) break;
        float r = acc[n] + bb;
        if (w == 0)      q[(size_t)nn * 64 + t] = r;
        else if (w == 1) ((ushort*)kvt)[((size_t)nn * 64 + t) * 2]     = f2bf(r);
        else if (w == 2) ((ushort*)kvt)[((size_t)nn * 64 + t) * 2 + 1] = f2bf(r);
        else             s[(size_t)nn * 64 + t] = r;
    }
}

// ---------------- layer 2: node linear (64 -> 16) x4 ----------------
// outputs: q [N,16] f32, kvt [N,16] uint packed, s [N,16] f32
__global__ __launch_bounds__(256) void node_lin2(const float* __restrict__ h,
                          const float* __restrict__ Wq, const float* __restrict__ bq,
                          const float* __restrict__ Wk, const float* __restrict__ bk,
                          const float* __restrict__ Wv, const float* __restrict__ bv,
                          const float* __restrict__ Ws, const float* __restrict__ bs,
                          float* __restrict__ q, uint* __restrict__ kvt,
                          float* __restrict__ s) {
    __shared__ float hs[32][65];
    int tid = threadIdx.x;
    int nb = blockIdx.x * 32;
    for (int i = tid; i < 32 * 64; i += 256) {
        int nn = nb + (i >> 6);
        hs[i >> 6][i & 63] = (nn < N_NODES) ? h[(size_t)nb * 64 + i] : 0.f;
    }
    __syncthreads();
    int w = tid >> 6, t = tid & 63, g = t >> 4, c = t & 15;
    const float* W = (w == 0) ? Wq : (w == 1) ? Wk : (w == 2) ? Wv : Ws;
    const float* b = (w == 0) ? bq : (w == 1) ? bk : (w == 2) ? bv : bs;
    float acc[8];
#pragma unroll
    for (int n = 0; n < 8; ++n) acc[n] = 0.f;
#pragma unroll 4
    for (int j = 0; j < 64; ++j) {
        float wv = W[j * 16 + c];
#pragma unroll
        for (int n = 0; n < 8; ++n) acc[n] += hs[g * 8 + n][j] * wv;
    }
    float bb = b[c];
#pragma unroll
    for (int n = 0; n < 8; ++n) {
        int nn = nb + g * 8 + n;
        if (nn >= N_NODES) break;
        float r = acc[n] + bb;
        if (w == 0)      q[(size_t)nn * 16 + c] = r;
        else if (w == 1) ((ushort*)kvt)[((size_t)nn * 16 + c) * 2]     = f2bf(r);
        else if (w == 2) ((ushort*)kvt)[((size_t)nn * 16 + c) * 2 + 1] = f2bf(r);
        else             s[(size_t)nn * 16 + c] = r;
    }
}

// ---------------- CSR build: histogram -> scan -> scatter ----------------
__global__ void hist_kernel(const int* __restrict__ ei, int* __restrict__ deg) {
    int e = blockIdx.x * blockDim.x + threadIdx.x;
    if (e < N_EDGES) atomicAdd(deg + ei[N_EDGES + e], 1);
}

__global__ __launch_bounds__(256) void scan_block(const int* __restrict__ deg,
        int* __restrict__ rowptr, int* __restrict__ bsum) {
    __shared__ int sd[256];
    int i = blockIdx.x * 256 + threadIdx.x;
    int v = (i < N_NODES) ? deg[i] : 0;
    sd[threadIdx.x] = v;
    __syncthreads();
    for (int off = 1; off < 256; off <<= 1) {
        int add = (threadIdx.x >= off) ? sd[threadIdx.x - off] : 0;
        __syncthreads();
        sd[threadIdx.x] += add;
        __syncthreads();
    }
    if (i < N_NODES) rowptr[i] = sd[threadIdx.x] - v;   // exclusive within block
    if (threadIdx.x == 255) bsum[blockIdx.x] = sd[255];
}

__global__ __launch_bounds__(512) void scan_bsum(int* __restrict__ bsum) {
    __shared__ int sd[512];
    int t = threadIdx.x;
    int v = (t < NB_SCAN) ? bsum[t] : 0;
    sd[t] = v;
    __syncthreads();
    for (int off = 1; off < 512; off <<= 1) {
        int add = (t >= off) ? sd[t - off] : 0;
        __syncthreads();
        sd[t] += add;
        __syncthreads();
    }
    if (t < NB_SCAN) bsum[t] = sd[t] - v;               // exclusive
}

__global__ void scan_add(int* __restrict__ rowptr, int* __restrict__ cursor,
                         const int* __restrict__ bsum) {
    int i = blockIdx.x * blockDim.x + threadIdx.x;
    if (i < N_NODES) {
        int r = rowptr[i] + bsum[i >> 8];
        rowptr[i] = r;
        cursor[i] = r;
    }
    if (i == 0) rowptr[N_NODES] = N_EDGES;
}

__global__ void scatter_kernel(const int* __restrict__ ei, int* __restrict__ cursor,
                               int2* __restrict__ sorted) {
    int e = blockIdx.x * blockDim.x + threadIdx.x;
    if (e >= N_EDGES) return;
    int d = ei[N_EDGES + e];
    int pos = atomicAdd(cursor + d, 1);
    sorted[pos] = make_int2(ei[e], e);   // (src, eid)
}

// ---------------- permute edge_attr into CSR order, packed bf16x2 ----------------
// eas[p][16] uints = 32 bf16 channels of edge at sorted position p
__global__ __launch_bounds__(256) void permute_ea(const int2* __restrict__ sorted,
        const float* __restrict__ ea, uint* __restrict__ eas) {
    int p = blockIdx.x * blockDim.x + threadIdx.x;
    if (p >= N_EDGES) return;
    int eid = sorted[p].y;
    const float4* src = (const float4*)(ea + (size_t)eid * 32);
    uint4* dst = (uint4*)(eas + (size_t)p * 16);
#pragma unroll
    for (int r = 0; r < 4; ++r) {
        float4 a = src[2 * r], b = src[2 * r + 1];
        uint4 o;
        o.x = (uint)f2bf(a.x) | ((uint)f2bf(a.y) << 16);
        o.y = (uint)f2bf(a.z) | ((uint)f2bf(a.w) << 16);
        o.z = (uint)f2bf(b.x) | ((uint)f2bf(b.y) << 16);
        o.w = (uint)f2bf(b.z) | ((uint)f2bf(b.w) << 16);
        dst[r] = o;
    }
}

// ---------------- layer 1: per-dst fused attention, 2-edge ILP ----------------
// one wave per dst node; 64 lanes = 64 channels; kvt packed bf16x2; eas sequential
__global__ __launch_bounds__(256) void agg_l1(const int2* __restrict__ sorted,
        const int* __restrict__ rowptr, const uint* __restrict__ eas,
        const float* __restrict__ q, const uint* __restrict__ kvt,
        const float* __restrict__ We, float* __restrict__ h) {
    int w = threadIdx.x >> 6, t = threadIdx.x & 63;
    int n = blockIdx.x * 4 + w;
    if (n >= N_NODES) return;
    float we[32];
#pragma unroll
    for (int j = 0; j < 32; ++j) we[j] = We[j * 64 + t];
    float qv = q[(size_t)n * 64 + t];
    int beg = rowptr[n], end = rowptr[n + 1];
    float den = 0.f, acc = 0.f;
    int idx = beg;
    for (; idx + 2 <= end; idx += 2) {
        int s0 = sorted[idx].x, s1 = sorted[idx + 1].x;
        uint kv0 = kvt[(size_t)s0 * 64 + t];
        uint kv1p = kvt[(size_t)s1 * 64 + t];
        const uint4* ep0 = (const uint4*)(eas + (size_t)idx * 16);
        const uint4* ep1 = ep0 + 4;
        float et0 = 0.f, et1 = 0.f;
#pragma unroll
        for (int r = 0; r < 4; ++r) {
            uint4 u0 = ep0[r], u1 = ep1[r];
            float w0 = we[8*r], w1 = we[8*r+1], w2 = we[8*r+2], w3 = we[8*r+3];
            float w4 = we[8*r+4], w5 = we[8*r+5], w6 = we[8*r+6], w7 = we[8*r+7];
            et0 += bf2f((ushort)u0.x) * w0 + bf2f((ushort)(u0.x >> 16)) * w1
                 + bf2f((ushort)u0.y) * w2 + bf2f((ushort)(u0.y >> 16)) * w3
                 + bf2f((ushort)u0.z) * w4 + bf2f((ushort)(u0.z >> 16)) * w5
                 + bf2f((ushort)u0.w) * w6 + bf2f((ushort)(u0.w >> 16)) * w7;
            et1 += bf2f((ushort)u1.x) * w0 + bf2f((ushort)(u1.x >> 16)) * w1
                 + bf2f((ushort)u1.y) * w2 + bf2f((ushort)(u1.y >> 16)) * w3
                 + bf2f((ushort)u1.z) * w4 + bf2f((ushort)(u1.z >> 16)) * w5
                 + bf2f((ushort)u1.w) * w6 + bf2f((ushort)(u1.w >> 16)) * w7;
        }
        float k0 = bf2f((ushort)kv0),  v0 = bf2f((ushort)(kv0 >> 16));
        float k1 = bf2f((ushort)kv1p), v1 = bf2f((ushort)(kv1p >> 16));
        float p0 = qv * (k0 + et0), p1 = qv * (k1 + et1);
#pragma unroll
        for (int m = 32; m > 0; m >>= 1) {
            p0 += __shfl_xor(p0, m, 64);
            p1 += __shfl_xor(p1, m, 64);
        }
        float a0 = __expf(p0 * 0.125f), a1 = __expf(p1 * 0.125f);
        den += a0 + a1;
        acc += a0 * (v0 + et0) + a1 * (v1 + et1);
    }
    if (idx < end) {
        int s0 = sorted[idx].x;
        uint kv0 = kvt[(size_t)s0 * 64 + t];
        const uint4* ep0 = (const uint4*)(eas + (size_t)idx * 16);
        float et0 = 0.f;
#pragma unroll
        for (int r = 0; r < 4; ++r) {
            uint4 u0 = ep0[r];
            et0 += bf2f((ushort)u0.x) * we[8*r]   + bf2f((ushort)(u0.x >> 16)) * we[8*r+1]
                 + bf2f((ushort)u0.y) * we[8*r+2] + bf2f((ushort)(u0.y >> 16)) * we[8*r+3]
                 + bf2f((ushort)u0.z) * we[8*r+4] + bf2f((ushort)(u0.z >> 16)) * we[8*r+5]
                 + bf2f((ushort)u0.w) * we[8*r+6] + bf2f((ushort)(u0.w >> 16)) * we[8*r+7];
        }
        float k0 = bf2f((ushort)kv0), v0 = bf2f((ushort)(kv0 >> 16));
        float p0 = qv * (k0 + et0);
#pragma unroll
        for (int m = 32; m > 0; m >>= 1) p0 += __shfl_xor(p0, m, 64);
        float a0 = __expf(p0 * 0.125f);
        den += a0;
        acc += a0 * (v0 + et0);
    }
    size_t o = (size_t)n * 64 + t;
    float r2 = acc / (den + 1e-16f) + h[o];
    h[o] = r2 > 0.f ? r2 : 0.f;
}

// ---------------- layer 2: per-dst fused attention + mean-pool ----------------
// one wave per dst; 4 groups x 16 lanes; kvt packed; eas sequential
__global__ __launch_bounds__(256) void agg_l2(const int2* __restrict__ sorted,
        const int* __restrict__ rowptr, const uint* __restrict__ eas,
        const float* __restrict__ q, const uint* __restrict__ kvt,
        const float* __restrict__ We, const float* __restrict__ skip,
        const int* __restrict__ batch, float* __restrict__ sums,
        float* __restrict__ cnt) {
    int w = threadIdx.x >> 6, t = threadIdx.x & 63;
    int n = blockIdx.x * 4 + w;
    if (n >= N_NODES) return;
    int g = t >> 4, c = t & 15;
    float we[32];
#pragma unroll
    for (int j = 0; j < 32; ++j) we[j] = We[j * 16 + c];
    float qv = q[(size_t)n * 16 + c];
    int beg = rowptr[n], end = rowptr[n + 1];
    float den = 0.f, acc = 0.f;
    for (int idx = beg + g; idx < end; idx += 4) {
        int s = sorted[idx].x;
        uint kvp = kvt[(size_t)s * 16 + c];
        const uint4* ep = (const uint4*)(eas + (size_t)idx * 16);
        float et = 0.f;
#pragma unroll
        for (int r = 0; r < 4; ++r) {
            uint4 u = ep[r];
            et += bf2f((ushort)u.x) * we[8*r]   + bf2f((ushort)(u.x >> 16)) * we[8*r+1]
                + bf2f((ushort)u.y) * we[8*r+2] + bf2f((ushort)(u.y >> 16)) * we[8*r+3]
                + bf2f((ushort)u.z) * we[8*r+4] + bf2f((ushort)(u.z >> 16)) * we[8*r+5]
                + bf2f((ushort)u.w) * we[8*r+6] + bf2f((ushort)(u.w >> 16)) * we[8*r+7];
        }
        float kx = bf2f((ushort)kvp), vx = bf2f((ushort)(kvp >> 16));
        float p = qv * (kx + et);
        p += __shfl_xor(p, 8, 64);
        p += __shfl_xor(p, 4, 64);
        p += __shfl_xor(p, 2, 64);
        p += __shfl_xor(p, 1, 64);
        float a = __expf(p * 0.25f);
        den += a;
        acc += a * (vx + et);
    }
    den += __shfl_xor(den, 16, 64);
    den += __shfl_xor(den, 32, 64);
    acc += __shfl_xor(acc, 16, 64);
    acc += __shfl_xor(acc, 32, 64);
    if (t < 16) {
        float r2 = acc / (den + 1e-16f) + skip[(size_t)n * 16 + c];
        r2 = r2 > 0.f ? r2 : 0.f;
        int gb = batch[n];
        atomicAdd(sums + gb * 16 + c, r2);
        if (c == 0) atomicAdd(cnt + gb, 1.0f);
    }
}

// ---------------- final fc + sigmoid ----------------
__global__ void final_fc(const float* __restrict__ sums, const float* __restrict__ cnt,
                         const float* __restrict__ Wf, const float* __restrict__ bf,
                         float* __restrict__ out) {
    int g = blockIdx.x * blockDim.x + threadIdx.x;
    if (g >= N_GRAPHS) return;
    float cc = cnt[g];
    cc = cc > 1.f ? cc : 1.f;
    float acc = bf[0];
#pragma unroll
    for (int c = 0; c < 16; ++c) acc += (sums[g * 16 + c] / cc) * Wf[c];
    out[g] = 1.f / (1.f + expf(-acc));
}

extern "C" void kernel_launch(void* const* d_in, const int* in_sizes, int n_in,
                              void* d_out, int out_size, void* d_ws, size_t ws_size,
                              hipStream_t stream) {
    const float* x    = (const float*)d_in[0];
    const float* ea   = (const float*)d_in[1];
    const float* Wq1  = (const float*)d_in[2];
    const float* bq1  = (const float*)d_in[3];
    const float* Wk1  = (const float*)d_in[4];
    const float* bk1  = (const float*)d_in[5];
    const float* Wv1  = (const float*)d_in[6];
    const float* bv1  = (const float*)d_in[7];
    const float* We1  = (const float*)d_in[8];
    const float* Ws1  = (const float*)d_in[9];
    const float* bs1  = (const float*)d_in[10];
    const float* Wq2  = (const float*)d_in[11];
    const float* bq2  = (const float*)d_in[12];
    const float* Wk2  = (const float*)d_in[13];
    const float* bk2  = (const float*)d_in[14];
    const float* Wv2  = (const float*)d_in[15];
    const float* bv2  = (const float*)d_in[16];
    const float* We2  = (const float*)d_in[17];
    const float* Ws2  = (const float*)d_in[18];
    const float* bs2  = (const float*)d_in[19];
    const float* Wf   = (const float*)d_in[20];
    const float* bf   = (const float*)d_in[21];
    const int*   ei   = (const int*)d_in[22];
    const int*   batch= (const int*)d_in[23];
    float* out = (float*)d_out;

    // -------- workspace layout (~212 MB) --------
    float* ws = (float*)d_ws;
    size_t off = 0;
    float* q1  = ws + off;        off += (size_t)N_NODES * 64;
    uint* kvt1 = (uint*)(ws + off); off += (size_t)N_NODES * 64;
    float* s1  = ws + off;        off += (size_t)N_NODES * 64;   // skip -> h1
    float* q2  = ws + off;        off += (size_t)N_NODES * 16;
    uint* kvt2 = (uint*)(ws + off); off += (size_t)N_NODES * 16;
    float* s2  = ws + off;        off += (size_t)N_NODES * 16;
    int2* sorted = (int2*)(ws + off); off += (size_t)N_EDGES * 2;
    uint* eas  = (uint*)(ws + off);  off += (size_t)N_EDGES * 16;
    int* rowptr  = (int*)(ws + off);  off += N_NODES + 2;
    int* cursor  = (int*)(ws + off);  off += N_NODES;
    int* bsum    = (int*)(ws + off);  off += 512;
    // ---- contiguous zero block ----
    float* zerop = ws + off;
    int*   deg   = (int*)(ws + off);  off += N_NODES;
    float* sums  = ws + off;          off += (size_t)N_GRAPHS * 16;
    float* cnt   = ws + off;          off += N_GRAPHS;
    size_t zero_bytes = ((size_t)N_NODES + N_GRAPHS * 16 + N_GRAPHS) * sizeof(float);
    hipMemsetAsync(zerop, 0, zero_bytes, stream);

    // -------- CSR build (shared by both layers) --------
    hist_kernel<<<(N_EDGES + 255) / 256, 256, 0, stream>>>(ei, deg);
    scan_block<<<NB_SCAN, 256, 0, stream>>>(deg, rowptr, bsum);
    scan_bsum<<<1, 512, 0, stream>>>(bsum);
    scan_add<<<NB_SCAN, 256, 0, stream>>>(rowptr, cursor, bsum);
    scatter_kernel<<<(N_EDGES + 255) / 256, 256, 0, stream>>>(ei, cursor, sorted);
    permute_ea<<<(N_EDGES + 255) / 256, 256, 0, stream>>>(sorted, ea, eas);

    // -------- layer 1 --------
    node_lin1<<<(N_NODES + 15) / 16, 256, 0, stream>>>(x, Wq1, bq1, Wk1, bk1, Wv1, bv1,
                                                       Ws1, bs1, q1, kvt1, s1);
    agg_l1<<<(N_NODES + 3) / 4, 256, 0, stream>>>(sorted, rowptr, eas, q1, kvt1, We1, s1);

    // -------- layer 2 --------
    node_lin2<<<(N_NODES + 31) / 32, 256, 0, stream>>>(s1, Wq2, bq2, Wk2, bk2, Wv2, bv2,
                                                       Ws2, bs2, q2, kvt2, s2);
    agg_l2<<<(N_NODES + 3) / 4, 256, 0, stream>>>(sorted, rowptr, eas, q2, kvt2, We2,
                                                  s2, batch, sums, cnt);

    // -------- final fc --------
    final_fc<<<(N_GRAPHS + 255) / 256, 256, 0, stream>>>(sums, cnt, Wf, bf, out);
}